// Round 1
// baseline (89010.791 us; speedup 1.0000x reference)
//
#include <hip/hip_runtime.h>
#include <math.h>

#define BB 64
#define LL 256
#define EE 512
#define HH 1024
#define MM 2048
#define HSZ 64
#define RR 4
#define CIN 768
#define PO 1280
#define OO 1024
#define EPS 1e-5f
#define NCH 8
#define CHM (MM / NCH)   // 256 slots per chunk

// ---- workspace layout (float offsets) ----
#define WS_H      0                          // [2][64][1024] double-buffered h
#define WS_C      (WS_H + 2 * BB * HH)       // [64][1024]
#define WS_HN     (WS_C + BB * HH)           // [64][1024]
#define WS_CI     (WS_HN + BB * HH)          // [64][768]
#define WS_RV     (WS_CI + BB * CIN)         // [64][256]
#define WS_RKN    (WS_RV + BB * RR * HSZ)    // [64][4][64]
#define WS_WKN    (WS_RKN + BB * RR * HSZ)   // [64][64]
#define WS_ER     (WS_WKN + BB * HSZ)        // [64][64]
#define WS_AD     (WS_ER + BB * HSZ)         // [64][64]
#define WS_WSS    (WS_AD + BB * HSZ)         // [64]
#define WS_WPART  (WS_WSS + BB)              // [64][8][2]
#define WS_SW     (WS_WPART + BB * NCH * 2)  // [64][2048]
#define WS_SR     (WS_SW + BB * MM)          // [64][4][2048]
#define WS_RPART  (WS_SR + BB * RR * MM)     // [64][4][8][2]
#define WS_OROW   (WS_RPART + BB * RR * NCH * 2) // [64][1280]

// ---- d_out layout (float offsets) ----
#define OUT_Y    0
#define OUT_MEM  (BB * LL * OO)              // 16777216
#define OUT_HT   (OUT_MEM + BB * MM * HSZ)   // 25165824
#define OUT_CT   (OUT_HT + BB * HH)          // 25231360

__device__ __forceinline__ float sigm(float x) { return 1.0f / (1.0f + expf(-x)); }

// block reduction over 256 threads (4 waves of 64)
__device__ __forceinline__ float bsum(float v, volatile float* red) {
    __syncthreads();
    for (int o = 32; o > 0; o >>= 1) v += __shfl_down(v, o, 64);
    int w = threadIdx.x >> 6;
    if ((threadIdx.x & 63) == 0) red[w] = v;
    __syncthreads();
    return red[0] + red[1] + red[2] + red[3];
}

__device__ __forceinline__ float bmax(float v, volatile float* red) {
    __syncthreads();
    for (int o = 32; o > 0; o >>= 1) v = fmaxf(v, __shfl_down(v, o, 64));
    int w = threadIdx.x >> 6;
    if ((threadIdx.x & 63) == 0) red[w] = v;
    __syncthreads();
    return fmaxf(fmaxf(red[0], red[1]), fmaxf(red[2], red[3]));
}

__global__ __launch_bounds__(256) void k_zero(float* p, int n) {
    int i = blockIdx.x * blockDim.x + threadIdx.x;
    int st = gridDim.x * blockDim.x;
    for (; i < n; i += st) p[i] = 0.0f;
}

// ci = LN(concat(x_t, rv)); grid = 64 blocks (one per b)
__global__ __launch_bounds__(256) void k_ci(const float* __restrict__ x_emb,
                                            const float* __restrict__ rv,
                                            const float* __restrict__ g,
                                            const float* __restrict__ bt,
                                            float* __restrict__ ci, int t) {
    int b = blockIdx.x, tid = threadIdx.x;
    __shared__ float row[CIN];
    __shared__ float red[4];
    for (int i = tid; i < EE; i += 256) row[i] = x_emb[(b * LL + t) * EE + i];
    for (int i = tid; i < RR * HSZ; i += 256) row[EE + i] = rv[b * RR * HSZ + i];
    __syncthreads();
    float s = 0.f;
    for (int i = tid; i < CIN; i += 256) s += row[i];
    float mu = bsum(s, red) / CIN;
    float ss = 0.f;
    for (int i = tid; i < CIN; i += 256) { float d = row[i] - mu; ss += d * d; }
    float rstd = rsqrtf(bsum(ss, red) / CIN + EPS);
    for (int i = tid; i < CIN; i += 256)
        ci[b * CIN + i] = (row[i] - mu) * rstd * g[i] + bt[i];
}

// gates GEMM + LSTM pointwise. grid = dim3(64, 4): 64 col-groups (16 cols/gate) x 4 b-groups (16 b)
__global__ __launch_bounds__(256) void k_gates(const float* __restrict__ ci,
                                               const float* __restrict__ hprev,
                                               const float* __restrict__ w_ih,
                                               const float* __restrict__ w_hh,
                                               const float* __restrict__ b_ih,
                                               const float* __restrict__ b_hh,
                                               float* __restrict__ c,
                                               float* __restrict__ hnew) {
    int cg = blockIdx.x, bg = blockIdx.y, tid = threadIdx.x;
    int tb = tid >> 4;          // b-local 0..15
    int cq = tid & 15;          // col-quad 0..15
    int b0 = bg * 16, j0 = cg * 16;
    __shared__ float A[16][68];
    __shared__ float Wt[64][68];
    __shared__ float Gv[16][68];
    float acc0 = 0.f, acc1 = 0.f, acc2 = 0.f, acc3 = 0.f;
    int c0 = cq * 4;
    for (int ph = 0; ph < 2; ++ph) {
        const float* Asrc = ph ? hprev : ci;
        const float* Wsrc = ph ? w_hh : w_ih;
        int K = ph ? HH : CIN;
        for (int k0 = 0; k0 < K; k0 += 64) {
            __syncthreads();
            {   // A tile 16 x 64
                int ar = tid >> 4, ac = (tid & 15) << 2;
                float4 a4 = *(const float4*)&Asrc[(b0 + ar) * K + k0 + ac];
                *(float4*)&A[ar][ac] = a4;
            }
            for (int i = 0; i < 4; ++i) {  // W tile 64 cols x 64 k, transposed into LDS
                int idx = i * 256 + tid;
                int cc = idx >> 4;
                int kq = (idx & 15) << 2;
                int gate = cc >> 4, jl = cc & 15;
                float4 w4 = *(const float4*)&Wsrc[(gate * HH + j0 + jl) * K + k0 + kq];
                Wt[kq + 0][cc] = w4.x; Wt[kq + 1][cc] = w4.y;
                Wt[kq + 2][cc] = w4.z; Wt[kq + 3][cc] = w4.w;
            }
            __syncthreads();
            for (int kk = 0; kk < 16; ++kk) {
                float4 a4 = *(const float4*)&A[tb][kk * 4];
                float4 w;
                w = *(const float4*)&Wt[kk * 4 + 0][c0];
                acc0 += a4.x * w.x; acc1 += a4.x * w.y; acc2 += a4.x * w.z; acc3 += a4.x * w.w;
                w = *(const float4*)&Wt[kk * 4 + 1][c0];
                acc0 += a4.y * w.x; acc1 += a4.y * w.y; acc2 += a4.y * w.z; acc3 += a4.y * w.w;
                w = *(const float4*)&Wt[kk * 4 + 2][c0];
                acc0 += a4.z * w.x; acc1 += a4.z * w.y; acc2 += a4.z * w.z; acc3 += a4.z * w.w;
                w = *(const float4*)&Wt[kk * 4 + 3][c0];
                acc0 += a4.w * w.x; acc1 += a4.w * w.y; acc2 += a4.w * w.z; acc3 += a4.w * w.w;
            }
        }
    }
    {   // biases; all 4 cols of a thread are in the same gate
        int gate = c0 >> 4;
        int jbase = j0 + (c0 & 15);
        int r = gate * HH + jbase;
        acc0 += b_ih[r] + b_hh[r];
        acc1 += b_ih[r + 1] + b_hh[r + 1];
        acc2 += b_ih[r + 2] + b_hh[r + 2];
        acc3 += b_ih[r + 3] + b_hh[r + 3];
    }
    Gv[tb][c0] = acc0; Gv[tb][c0 + 1] = acc1; Gv[tb][c0 + 2] = acc2; Gv[tb][c0 + 3] = acc3;
    __syncthreads();
    {   // LSTM pointwise: thread handles (b-local=tb, j-local=cq)
        int jl = cq;
        float gi = Gv[tb][jl];
        float gf = Gv[tb][16 + jl];
        float gg = Gv[tb][32 + jl];
        float go = Gv[tb][48 + jl];
        int idx = (b0 + tb) * HH + j0 + jl;
        float cold = c[idx];
        float cn = sigm(gf) * cold + sigm(gi) * tanhf(gg);
        float hn = sigm(go) * tanhf(cn);
        c[idx] = cn;
        hnew[idx] = hn;
    }
}

// hn = LN(h_new); head projections; per-head LNs/activations. grid = 64 (per b)
__global__ __launch_bounds__(256) void k_hn_heads(
        const float* __restrict__ hnew, const float* __restrict__ ln_c_g, const float* __restrict__ ln_c_b,
        const float* __restrict__ w_rk, const float* __restrict__ b_rk,
        const float* __restrict__ w_wk, const float* __restrict__ b_wk,
        const float* __restrict__ w_ws, const float* __restrict__ b_ws,
        const float* __restrict__ w_er, const float* __restrict__ b_er,
        const float* __restrict__ w_ad, const float* __restrict__ b_ad,
        const float* __restrict__ ln_rk_g, const float* __restrict__ ln_rk_b,
        const float* __restrict__ ln_wk_g, const float* __restrict__ ln_wk_b,
        float* __restrict__ hn_out, float* __restrict__ rkn, float* __restrict__ wkn,
        float* __restrict__ ers, float* __restrict__ ads, float* __restrict__ wss) {
    int b = blockIdx.x, tid = threadIdx.x;
    __shared__ float hrow[HH];
    __shared__ float red[4];
    __shared__ float raw[452];
    {
        float4 h4 = *(const float4*)&hnew[b * HH + tid * 4];
        *(float4*)&hrow[tid * 4] = h4;
    }
    __syncthreads();
    float s = 0.f;
    for (int i = tid; i < HH; i += 256) s += hrow[i];
    float mu = bsum(s, red) / HH;
    float ss = 0.f;
    for (int i = tid; i < HH; i += 256) { float d = hrow[i] - mu; ss += d * d; }
    float rstd = rsqrtf(bsum(ss, red) / HH + EPS);
    __syncthreads();
    for (int i = tid; i < HH; i += 256) {
        float v = (hrow[i] - mu) * rstd * ln_c_g[i] + ln_c_b[i];
        hrow[i] = v;
        hn_out[b * HH + i] = v;
    }
    __syncthreads();
    // 449 head rows: [0,256)=rk, [256,320)=wk, 320=ws, [321,385)=er, [385,449)=ad
    for (int r = tid; r < 449; r += 256) {
        const float* wrow; float bias;
        if (r < 256)      { wrow = &w_rk[r * HH];        bias = b_rk[r]; }
        else if (r < 320) { wrow = &w_wk[(r - 256) * HH]; bias = b_wk[r - 256]; }
        else if (r == 320){ wrow = w_ws;                  bias = b_ws[0]; }
        else if (r < 385) { wrow = &w_er[(r - 321) * HH]; bias = b_er[r - 321]; }
        else              { wrow = &w_ad[(r - 385) * HH]; bias = b_ad[r - 385]; }
        float acc = bias;
        for (int k = 0; k < HH; k += 4) {
            float4 w4 = *(const float4*)&wrow[k];
            acc += w4.x * hrow[k] + w4.y * hrow[k + 1] + w4.z * hrow[k + 2] + w4.w * hrow[k + 3];
        }
        raw[r] = acc;
    }
    __syncthreads();
    if (tid < 64) {
        // LN groups: 4 read-keys + write-key (each 64 wide), wave-wide reductions
        for (int gsel = 0; gsel < 5; ++gsel) {
            float v = raw[gsel * 64 + tid];
            float sv = v;
            for (int o = 32; o > 0; o >>= 1) sv += __shfl_xor(sv, o, 64);
            float m2 = sv / 64.f;
            float d = v - m2;
            float sq = d * d;
            for (int o = 32; o > 0; o >>= 1) sq += __shfl_xor(sq, o, 64);
            float rs = rsqrtf(sq / 64.f + EPS);
            if (gsel < 4) {
                float nv = d * rs * ln_rk_g[tid] + ln_rk_b[tid];
                rkn[(b * RR + gsel) * HSZ + tid] = nv;
            } else {
                float nv = d * rs * ln_wk_g[tid] + ln_wk_b[tid];
                wkn[b * HSZ + tid] = nv;
            }
        }
        ers[b * HSZ + tid] = sigm(raw[321 + tid]);
        ads[b * HSZ + tid] = tanhf(raw[385 + tid]);
        if (tid == 0) wss[b] = sigm(raw[320]);
    }
}

// write-attention scores + per-chunk softmax partials. grid = dim3(NCH, BB)
__global__ __launch_bounds__(256) void k_wscore(const float* __restrict__ mem,
                                                const float* __restrict__ wkn,
                                                const float* __restrict__ ln_m_g,
                                                const float* __restrict__ ln_m_b,
                                                float* __restrict__ s_w,
                                                float* __restrict__ wpart) {
    int ch = blockIdx.x, b = blockIdx.y, tid = threadIdx.x;
    int m = ch * CHM + tid;
    __shared__ float wk_s[64], g_s[64], bt_s[64];
    __shared__ float red[4];
    if (tid < 64) { wk_s[tid] = wkn[b * HSZ + tid]; g_s[tid] = ln_m_g[tid]; bt_s[tid] = ln_m_b[tid]; }
    __syncthreads();
    const float* row = &mem[(size_t)(b * MM + m) * HSZ];
    float4 v[16];
    float sum = 0.f;
    for (int i = 0; i < 16; ++i) {
        v[i] = *(const float4*)&row[i * 4];
        sum += v[i].x + v[i].y + v[i].z + v[i].w;
    }
    float mu = sum * (1.f / HSZ);
    float ssq = 0.f;
    for (int i = 0; i < 16; ++i) {
        float dx = v[i].x - mu, dy = v[i].y - mu, dz = v[i].z - mu, dw = v[i].w - mu;
        ssq += dx * dx + dy * dy + dz * dz + dw * dw;
    }
    float rstd = rsqrtf(ssq * (1.f / HSZ) + EPS);
    float sc = 0.f;
    for (int i = 0; i < 16; ++i) {
        int h = i * 4;
        sc += ((v[i].x - mu) * rstd * g_s[h] + bt_s[h]) * wk_s[h];
        sc += ((v[i].y - mu) * rstd * g_s[h + 1] + bt_s[h + 1]) * wk_s[h + 1];
        sc += ((v[i].z - mu) * rstd * g_s[h + 2] + bt_s[h + 2]) * wk_s[h + 2];
        sc += ((v[i].w - mu) * rstd * g_s[h + 3] + bt_s[h + 3]) * wk_s[h + 3];
    }
    s_w[b * MM + m] = sc;
    float mx = bmax(sc, red);
    float se = bsum(expf(sc - mx), red);
    if (tid == 0) { wpart[(b * NCH + ch) * 2] = mx; wpart[(b * NCH + ch) * 2 + 1] = se; }
}

// memory update + read scores + read-softmax partials. grid = dim3(NCH, BB)
__global__ __launch_bounds__(256) void k_update(float* __restrict__ mem,
                                                const float* __restrict__ s_w,
                                                const float* __restrict__ wpart,
                                                const float* __restrict__ ers,
                                                const float* __restrict__ ads,
                                                const float* __restrict__ wss,
                                                const float* __restrict__ rkn,
                                                const float* __restrict__ ln_m_g,
                                                const float* __restrict__ ln_m_b,
                                                float* __restrict__ s_r,
                                                float* __restrict__ rpart) {
    int ch = blockIdx.x, b = blockIdx.y, tid = threadIdx.x;
    int m = ch * CHM + tid;
    __shared__ float er_s[64], ad_s[64], g_s[64], bt_s[64], rk_s[4][64];
    __shared__ float red[4];
    if (tid < 64) { er_s[tid] = ers[b * HSZ + tid]; ad_s[tid] = ads[b * HSZ + tid];
                    g_s[tid] = ln_m_g[tid]; bt_s[tid] = ln_m_b[tid]; }
    rk_s[tid >> 6][tid & 63] = rkn[b * RR * HSZ + tid];
    __syncthreads();
    float gmx = -3.4e38f;
    for (int cc = 0; cc < NCH; ++cc) gmx = fmaxf(gmx, wpart[(b * NCH + cc) * 2]);
    float gsum = 0.f;
    for (int cc = 0; cc < NCH; ++cc)
        gsum += wpart[(b * NCH + cc) * 2 + 1] * expf(wpart[(b * NCH + cc) * 2] - gmx);
    float ww = expf(s_w[b * MM + m] - gmx) / gsum * wss[b];
    float* row = &mem[(size_t)(b * MM + m) * HSZ];
    float4 v[16];
    for (int i = 0; i < 16; ++i) v[i] = *(const float4*)&row[i * 4];
    float sum = 0.f;
    for (int i = 0; i < 16; ++i) {
        int h = i * 4;
        v[i].x = v[i].x * (1.f - ww * er_s[h])     + ww * ad_s[h];
        v[i].y = v[i].y * (1.f - ww * er_s[h + 1]) + ww * ad_s[h + 1];
        v[i].z = v[i].z * (1.f - ww * er_s[h + 2]) + ww * ad_s[h + 2];
        v[i].w = v[i].w * (1.f - ww * er_s[h + 3]) + ww * ad_s[h + 3];
        *(float4*)&row[i * 4] = v[i];
        sum += v[i].x + v[i].y + v[i].z + v[i].w;
    }
    float mu = sum * (1.f / HSZ);
    float ssq = 0.f;
    for (int i = 0; i < 16; ++i) {
        float dx = v[i].x - mu, dy = v[i].y - mu, dz = v[i].z - mu, dw = v[i].w - mu;
        ssq += dx * dx + dy * dy + dz * dz + dw * dw;
    }
    float rstd = rsqrtf(ssq * (1.f / HSZ) + EPS);
    float s0 = 0.f, s1 = 0.f, s2 = 0.f, s3 = 0.f;
    for (int i = 0; i < 16; ++i) {
        int h = i * 4;
        float n0 = (v[i].x - mu) * rstd * g_s[h] + bt_s[h];
        float n1 = (v[i].y - mu) * rstd * g_s[h + 1] + bt_s[h + 1];
        float n2 = (v[i].z - mu) * rstd * g_s[h + 2] + bt_s[h + 2];
        float n3 = (v[i].w - mu) * rstd * g_s[h + 3] + bt_s[h + 3];
        s0 += n0 * rk_s[0][h] + n1 * rk_s[0][h + 1] + n2 * rk_s[0][h + 2] + n3 * rk_s[0][h + 3];
        s1 += n0 * rk_s[1][h] + n1 * rk_s[1][h + 1] + n2 * rk_s[1][h + 2] + n3 * rk_s[1][h + 3];
        s2 += n0 * rk_s[2][h] + n1 * rk_s[2][h + 1] + n2 * rk_s[2][h + 2] + n3 * rk_s[2][h + 3];
        s3 += n0 * rk_s[3][h] + n1 * rk_s[3][h + 1] + n2 * rk_s[3][h + 2] + n3 * rk_s[3][h + 3];
    }
    s_r[(b * RR + 0) * MM + m] = s0;
    s_r[(b * RR + 1) * MM + m] = s1;
    s_r[(b * RR + 2) * MM + m] = s2;
    s_r[(b * RR + 3) * MM + m] = s3;
    float sv[4] = {s0, s1, s2, s3};
    for (int n = 0; n < RR; ++n) {
        float mx = bmax(sv[n], red);
        float se = bsum(expf(sv[n] - mx), red);
        if (tid == 0) {
            rpart[((b * RR + n) * NCH + ch) * 2] = mx;
            rpart[((b * RR + n) * NCH + ch) * 2 + 1] = se;
        }
    }
}

// read weighted sum. grid = dim3(RR, BB)
__global__ __launch_bounds__(256) void k_read(const float* __restrict__ mem,
                                              const float* __restrict__ s_r,
                                              const float* __restrict__ rpart,
                                              float* __restrict__ rv) {
    int n = blockIdx.x, b = blockIdx.y, tid = threadIdx.x;
    int hs = tid & 63, mi = tid >> 6;
    float gmx = -3.4e38f;
    for (int cc = 0; cc < NCH; ++cc) gmx = fmaxf(gmx, rpart[((b * RR + n) * NCH + cc) * 2]);
    float gsum = 0.f;
    for (int cc = 0; cc < NCH; ++cc)
        gsum += rpart[((b * RR + n) * NCH + cc) * 2 + 1] * expf(rpart[((b * RR + n) * NCH + cc) * 2] - gmx);
    float acc = 0.f;
    for (int m = mi; m < MM; m += 4) {
        float w = expf(s_r[(b * RR + n) * MM + m] - gmx);
        acc += w * mem[(size_t)(b * MM + m) * HSZ + hs];
    }
    __shared__ float part[4][65];
    part[mi][hs] = acc;
    __syncthreads();
    if (mi == 0) {
        float r = (part[0][hs] + part[1][hs] + part[2][hs] + part[3][hs]) / gsum;
        rv[b * RR * HSZ + n * HSZ + hs] = r;
    }
}

// out_row = LN(concat(hn, rv)). grid = 64 (per b)
__global__ __launch_bounds__(256) void k_orow(const float* __restrict__ hn,
                                              const float* __restrict__ rv,
                                              const float* __restrict__ g,
                                              const float* __restrict__ bt,
                                              float* __restrict__ orow) {
    int b = blockIdx.x, tid = threadIdx.x;
    __shared__ float row[PO];
    __shared__ float red[4];
    for (int i = tid; i < PO; i += 256)
        row[i] = (i < HH) ? hn[b * HH + i] : rv[b * RR * HSZ + i - HH];
    __syncthreads();
    float s = 0.f;
    for (int i = tid; i < PO; i += 256) s += row[i];
    float mu = bsum(s, red) / PO;
    float ss = 0.f;
    for (int i = tid; i < PO; i += 256) { float d = row[i] - mu; ss += d * d; }
    float rstd = rsqrtf(bsum(ss, red) / PO + EPS);
    for (int i = tid; i < PO; i += 256)
        orow[b * PO + i] = (row[i] - mu) * rstd * g[i] + bt[i];
}

// logits GEMM: orow[64,1280] @ w_p^T[1280,1024] + b_p -> y[b,t,:]. grid = dim3(16, 4)
__global__ __launch_bounds__(256) void k_logits(const float* __restrict__ orow,
                                                const float* __restrict__ w_p,
                                                const float* __restrict__ b_p,
                                                float* __restrict__ y, int t) {
    int cg = blockIdx.x, bg = blockIdx.y, tid = threadIdx.x;
    int tb = tid >> 4, cq = tid & 15;
    int b0 = bg * 16, col0 = cg * 64;
    __shared__ float A[16][68];
    __shared__ float Wt[64][68];
    float acc0 = 0.f, acc1 = 0.f, acc2 = 0.f, acc3 = 0.f;
    int c0 = cq * 4;
    for (int k0 = 0; k0 < PO; k0 += 64) {
        __syncthreads();
        {
            int ar = tid >> 4, ac = (tid & 15) << 2;
            float4 a4 = *(const float4*)&orow[(b0 + ar) * PO + k0 + ac];
            *(float4*)&A[ar][ac] = a4;
        }
        for (int i = 0; i < 4; ++i) {
            int idx = i * 256 + tid;
            int cc = idx >> 4;
            int kq = (idx & 15) << 2;
            float4 w4 = *(const float4*)&w_p[(col0 + cc) * PO + k0 + kq];
            Wt[kq + 0][cc] = w4.x; Wt[kq + 1][cc] = w4.y;
            Wt[kq + 2][cc] = w4.z; Wt[kq + 3][cc] = w4.w;
        }
        __syncthreads();
        for (int kk = 0; kk < 16; ++kk) {
            float4 a4 = *(const float4*)&A[tb][kk * 4];
            float4 w;
            w = *(const float4*)&Wt[kk * 4 + 0][c0];
            acc0 += a4.x * w.x; acc1 += a4.x * w.y; acc2 += a4.x * w.z; acc3 += a4.x * w.w;
            w = *(const float4*)&Wt[kk * 4 + 1][c0];
            acc0 += a4.y * w.x; acc1 += a4.y * w.y; acc2 += a4.y * w.z; acc3 += a4.y * w.w;
            w = *(const float4*)&Wt[kk * 4 + 2][c0];
            acc0 += a4.z * w.x; acc1 += a4.z * w.y; acc2 += a4.z * w.z; acc3 += a4.z * w.w;
            w = *(const float4*)&Wt[kk * 4 + 3][c0];
            acc0 += a4.w * w.x; acc1 += a4.w * w.y; acc2 += a4.w * w.z; acc3 += a4.w * w.w;
        }
    }
    int col = col0 + c0;
    float4 out;
    out.x = acc0 + b_p[col];
    out.y = acc1 + b_p[col + 1];
    out.z = acc2 + b_p[col + 2];
    out.w = acc3 + b_p[col + 3];
    *(float4*)&y[(size_t)((b0 + tb) * LL + t) * OO + col] = out;
}

__global__ __launch_bounds__(256) void k_final(const float* __restrict__ h,
                                               const float* __restrict__ c,
                                               float* __restrict__ ht,
                                               float* __restrict__ ct) {
    int i = blockIdx.x * 256 + threadIdx.x;
    if (i < BB * HH) { ht[i] = h[i]; ct[i] = c[i]; }
}

extern "C" void kernel_launch(void* const* d_in, const int* in_sizes, int n_in,
                              void* d_out, int out_size, void* d_ws, size_t ws_size,
                              hipStream_t stream) {
    const float* x_emb  = (const float*)d_in[0];
    const float* ln_in_g = (const float*)d_in[1];
    const float* ln_in_b = (const float*)d_in[2];
    const float* w_ih   = (const float*)d_in[3];
    const float* w_hh   = (const float*)d_in[4];
    const float* b_ih   = (const float*)d_in[5];
    const float* b_hh   = (const float*)d_in[6];
    const float* ln_c_g = (const float*)d_in[7];
    const float* ln_c_b = (const float*)d_in[8];
    const float* w_rk   = (const float*)d_in[9];
    const float* b_rk   = (const float*)d_in[10];
    const float* w_wk   = (const float*)d_in[11];
    const float* b_wk   = (const float*)d_in[12];
    const float* w_ws   = (const float*)d_in[13];
    const float* b_ws   = (const float*)d_in[14];
    const float* w_er   = (const float*)d_in[15];
    const float* b_er   = (const float*)d_in[16];
    const float* w_ad   = (const float*)d_in[17];
    const float* b_ad   = (const float*)d_in[18];
    const float* ln_rk_g = (const float*)d_in[19];
    const float* ln_rk_b = (const float*)d_in[20];
    const float* ln_wk_g = (const float*)d_in[21];
    const float* ln_wk_b = (const float*)d_in[22];
    const float* ln_m_g = (const float*)d_in[23];
    const float* ln_m_b = (const float*)d_in[24];
    const float* ln_o_g = (const float*)d_in[25];
    const float* ln_o_b = (const float*)d_in[26];
    const float* w_p    = (const float*)d_in[27];
    const float* b_p    = (const float*)d_in[28];

    float* ws = (float*)d_ws;
    float* out = (float*)d_out;

    float* h    = ws + WS_H;
    float* c    = ws + WS_C;
    float* hn   = ws + WS_HN;
    float* ci   = ws + WS_CI;
    float* rv   = ws + WS_RV;
    float* rkn  = ws + WS_RKN;
    float* wkn  = ws + WS_WKN;
    float* ers  = ws + WS_ER;
    float* ads  = ws + WS_AD;
    float* wss  = ws + WS_WSS;
    float* wpart = ws + WS_WPART;
    float* s_w  = ws + WS_SW;
    float* s_r  = ws + WS_SR;
    float* rpart = ws + WS_RPART;
    float* orow = ws + WS_OROW;

    float* y    = out + OUT_Y;
    float* mem  = out + OUT_MEM;   // memT lives directly in d_out
    float* ht   = out + OUT_HT;
    float* ct   = out + OUT_CT;

    // zero initial state
    k_zero<<<64, 256, 0, stream>>>(h, BB * HH);          // only h[0] read at t=0
    k_zero<<<64, 256, 0, stream>>>(c, BB * HH);
    k_zero<<<16, 256, 0, stream>>>(rv, BB * RR * HSZ);
    k_zero<<<2048, 256, 0, stream>>>(mem, BB * MM * HSZ);

    for (int t = 0; t < LL; ++t) {
        int cur = t & 1, nxt = 1 - cur;
        float* hprev = h + cur * BB * HH;
        float* hnew  = h + nxt * BB * HH;
        k_ci<<<64, 256, 0, stream>>>(x_emb, rv, ln_in_g, ln_in_b, ci, t);
        k_gates<<<dim3(64, 4), 256, 0, stream>>>(ci, hprev, w_ih, w_hh, b_ih, b_hh, c, hnew);
        k_hn_heads<<<64, 256, 0, stream>>>(hnew, ln_c_g, ln_c_b,
                                           w_rk, b_rk, w_wk, b_wk, w_ws, b_ws,
                                           w_er, b_er, w_ad, b_ad,
                                           ln_rk_g, ln_rk_b, ln_wk_g, ln_wk_b,
                                           hn, rkn, wkn, ers, ads, wss);
        k_wscore<<<dim3(NCH, BB), 256, 0, stream>>>(mem, wkn, ln_m_g, ln_m_b, s_w, wpart);
        k_update<<<dim3(NCH, BB), 256, 0, stream>>>(mem, s_w, wpart, ers, ads, wss, rkn,
                                                    ln_m_g, ln_m_b, s_r, rpart);
        k_read<<<dim3(RR, BB), 256, 0, stream>>>(mem, s_r, rpart, rv);
        k_orow<<<64, 256, 0, stream>>>(hn, rv, ln_o_g, ln_o_b, orow);
        k_logits<<<dim3(16, 4), 256, 0, stream>>>(orow, w_p, b_p, y, t);
    }
    // after t=255 (odd), final h is in buffer 0
    k_final<<<256, 256, 0, stream>>>(h, c, ht, ct);
}